// Round 1
// 1408.205 us; speedup vs baseline: 1.4189x; 1.4189x over previous
//
#include <hip/hip_runtime.h>
#include <math.h>

// Problem constants (B=2, S=2048, D=1024, H=16, DH=64)
#define Bb 2
#define Ss 2048
#define Dd 1024
#define Hh 16
#define DHh 64

typedef unsigned short u16;
typedef unsigned int u32;
typedef __attribute__((ext_vector_type(8))) short short8;   // 8 bf16 = 4 VGPR
typedef __attribute__((ext_vector_type(4))) float f32x4;

__device__ __forceinline__ u16 fb(float f){
    u32 x = __float_as_uint(f);
    return (u16)((x + 0x7fffu + ((x>>16)&1u)) >> 16);   // RNE bf16
}
__device__ __forceinline__ u32 pack2(float a, float b){
    return (u32)fb(a) | ((u32)fb(b)<<16);
}
__device__ __forceinline__ void unpack8(uint4 v, float* f){
    f[0]=__uint_as_float(v.x<<16); f[1]=__uint_as_float(v.x&0xffff0000u);
    f[2]=__uint_as_float(v.y<<16); f[3]=__uint_as_float(v.y&0xffff0000u);
    f[4]=__uint_as_float(v.z<<16); f[5]=__uint_as_float(v.z&0xffff0000u);
    f[6]=__uint_as_float(v.w<<16); f[7]=__uint_as_float(v.w&0xffff0000u);
}

// ---------------------------------------------------------------------------
// C[M,N] = A[M,K] @ W[N,K]^T + bias.
// ABF16: A is bf16 (ws intermediate) vs fp32 (harness input).
// MODE 0: fp32 row-major store. MODE 1: bf16 split-head store [B,H,S,DH].
// MODE 2: bf16 split-head TRANSPOSED store [B,H,DH,S] (for V -> PV B-frags).
// ---------------------------------------------------------------------------
template<int ABF16, int MODE>
__global__ __launch_bounds__(256) void gemm_at(
    const void* __restrict__ Av, const float* __restrict__ W,
    const float* __restrict__ bias, void* __restrict__ outv,
    int M, int N, int K)
{
    __shared__ float As[16][132];
    __shared__ float Wsh[16][132];
    const int t = threadIdx.x;
    const int ty = t >> 4, tx = t & 15;
    const int bm = blockIdx.x, bn = blockIdx.y;
    const int lr = t >> 1;          // 0..127
    const int lc = (t & 1) * 8;     // 0 or 8
    const float* Wp = W + (size_t)(bn*128 + lr) * K + lc;

    float acc[8][8];
    #pragma unroll
    for (int i=0;i<8;i++)
        #pragma unroll
        for (int j=0;j<8;j++) acc[i][j]=0.f;

    for (int kt=0; kt<K; kt+=16){
        float af[8], wf[8];
        if (ABF16){
            const u16* Ap = (const u16*)Av + (size_t)(bm*128 + lr) * K + lc;
            uint4 av = *(const uint4*)(Ap + kt);
            unpack8(av, af);
        } else {
            const float* Ap = (const float*)Av + (size_t)(bm*128 + lr) * K + lc;
            float4 a0 = *(const float4*)(Ap + kt);
            float4 a1 = *(const float4*)(Ap + kt + 4);
            af[0]=a0.x; af[1]=a0.y; af[2]=a0.z; af[3]=a0.w;
            af[4]=a1.x; af[5]=a1.y; af[6]=a1.z; af[7]=a1.w;
        }
        {
            float4 w0 = *(const float4*)(Wp + kt);
            float4 w1 = *(const float4*)(Wp + kt + 4);
            wf[0]=w0.x; wf[1]=w0.y; wf[2]=w0.z; wf[3]=w0.w;
            wf[4]=w1.x; wf[5]=w1.y; wf[6]=w1.z; wf[7]=w1.w;
        }
        __syncthreads();
        #pragma unroll
        for (int i=0;i<8;i++){ As[lc+i][lr]=af[i]; Wsh[lc+i][lr]=wf[i]; }
        __syncthreads();
        #pragma unroll
        for (int kk=0;kk<16;kk++){
            float4 a0=*(const float4*)&As[kk][ty*8];
            float4 a1=*(const float4*)&As[kk][ty*8+4];
            float4 b0=*(const float4*)&Wsh[kk][tx*8];
            float4 b1=*(const float4*)&Wsh[kk][tx*8+4];
            float a[8]={a0.x,a0.y,a0.z,a0.w,a1.x,a1.y,a1.z,a1.w};
            float c[8]={b0.x,b0.y,b0.z,b0.w,b1.x,b1.y,b1.z,b1.w};
            #pragma unroll
            for (int i=0;i<8;i++)
                #pragma unroll
                for (int j=0;j<8;j++) acc[i][j] = fmaf(a[i], c[j], acc[i][j]);
        }
    }

    const int n0 = bn*128 + tx*8;
    float4 bv0 = *(const float4*)(bias + n0);
    float4 bv1 = *(const float4*)(bias + n0 + 4);
    float bb8[8] = {bv0.x,bv0.y,bv0.z,bv0.w,bv1.x,bv1.y,bv1.z,bv1.w};

    if (MODE==2){
        // transposed bf16 store: vt[(b*H+h)*DH + d][s]
        const int mbase = bm*128 + ty*8;
        const int bI = mbase >> 11, s = mbase & (Ss-1);
        const int h = n0 >> 6, d0 = n0 & (DHh-1);
        u16* vt = (u16*)outv;
        #pragma unroll
        for (int j=0;j<8;j++){
            uint4 sv;
            sv.x = pack2(acc[0][j]+bb8[j], acc[1][j]+bb8[j]);
            sv.y = pack2(acc[2][j]+bb8[j], acc[3][j]+bb8[j]);
            sv.z = pack2(acc[4][j]+bb8[j], acc[5][j]+bb8[j]);
            sv.w = pack2(acc[6][j]+bb8[j], acc[7][j]+bb8[j]);
            *(uint4*)(vt + ((size_t)((bI*Hh + h)*DHh + d0 + j))*Ss + s) = sv;
        }
        return;
    }

    #pragma unroll
    for (int i=0;i<8;i++){
        const int m = bm*128 + ty*8 + i;
        float r[8];
        #pragma unroll
        for (int j=0;j<8;j++) r[j] = acc[i][j] + bb8[j];
        if (MODE==0){
            float* op = (float*)outv + (size_t)m*N + n0;
            *(float4*)op     = make_float4(r[0],r[1],r[2],r[3]);
            *(float4*)(op+4) = make_float4(r[4],r[5],r[6],r[7]);
        } else {
            const int b = m >> 11, s = m & (Ss-1);
            const int h = n0 >> 6, d = n0 & (DHh-1);
            uint4 sv;
            sv.x = pack2(r[0],r[1]); sv.y = pack2(r[2],r[3]);
            sv.z = pack2(r[4],r[5]); sv.w = pack2(r[6],r[7]);
            *(uint4*)((u16*)outv + ((size_t)((b*Hh + h)*Ss + s))*DHh + d) = sv;
        }
    }
}

// ---------------------------------------------------------------------------
// mask [B,1,S,S] int32 -> bitmask [B,S,S/32] (removes ~536 MB/pass L3 traffic)
// ---------------------------------------------------------------------------
__global__ __launch_bounds__(256) void mask_pack(
    const int* __restrict__ mask, u32* __restrict__ mbits)
{
    const size_t w = (size_t)blockIdx.x*256 + threadIdx.x;
    const int* p = mask + w*32;
    u32 bits = 0;
    #pragma unroll
    for (int i=0;i<32;i+=4){
        int4 v = *(const int4*)(p + i);
        bits |= (u32)(v.x!=0) << i;
        bits |= (u32)(v.y!=0) << (i+1);
        bits |= (u32)(v.z!=0) << (i+2);
        bits |= (u32)(v.w!=0) << (i+3);
    }
    mbits[w] = bits;
}

// ---------------------------------------------------------------------------
// S1: per-row softmax stats (m,l) via MFMA QK^T. No LDS.
// Block = 4 waves x 32 q-rows = 128 q-rows; all 2048 keys per block.
// Fragment mapping (16x16x32 bf16): A row = lane&15, k = (lane>>4)*8+i;
// B col = lane&15, k = (lane>>4)*8+i; C col = lane&15, row = (lane>>4)*4+reg.
// ---------------------------------------------------------------------------
__global__ __launch_bounds__(256) void attn_stats_mfma(
    const u16* __restrict__ Q, const u16* __restrict__ K,
    const u32* __restrict__ mbits,
    float* __restrict__ mstat, float* __restrict__ lstat)
{
    const int t = threadIdx.x;
    const int lane = t & 63, wave = t >> 6;
    const int qt = blockIdx.x, bh = blockIdx.y;
    const int b = bh >> 4;
    const int qr0 = qt*128 + wave*32;
    const u16* qb = Q + ((size_t)bh*Ss + qr0)*DHh;
    const u16* kb = K + (size_t)bh*Ss*DHh;
    const u32* mb = mbits + (size_t)b*Ss*(Ss/32);

    const int lr = lane & 15;      // A/B row|col within tile
    const int lg = lane >> 4;      // k-chunk group / C row group

    short8 aq[2][2];
    #pragma unroll
    for (int s2=0;s2<2;s2++)
        #pragma unroll
        for (int dh=0; dh<2; dh++)
            aq[s2][dh] = *(const short8*)(qb + (size_t)(s2*16 + lr)*DHh + dh*32 + lg*8);

    int qv[8];
    #pragma unroll
    for (int idx=0; idx<8; idx++)
        qv[idx] = qr0 + (idx>>2)*16 + lg*4 + (idx&3);

    float m[8], l[8];
    #pragma unroll
    for (int i=0;i<8;i++){ m[i]=-1e30f; l[i]=0.f; }

    for (int k0=0; k0<Ss; k0+=32){
        u32 mw[8];
        #pragma unroll
        for (int idx=0; idx<8; idx++)
            mw[idx] = mb[(size_t)qv[idx]*(Ss/32) + (k0>>5)];
        #pragma unroll
        for (int h2=0; h2<2; h2++){
            const u16* kr = kb + (size_t)(k0 + h2*16 + lr)*DHh + lg*8;
            short8 b0 = *(const short8*)kr;
            short8 b1 = *(const short8*)(kr + 32);
            f32x4 z = {0.f,0.f,0.f,0.f};
            f32x4 s0 = __builtin_amdgcn_mfma_f32_16x16x32_bf16(aq[0][0], b0, z, 0,0,0);
            s0 = __builtin_amdgcn_mfma_f32_16x16x32_bf16(aq[0][1], b1, s0, 0,0,0);
            f32x4 s1 = __builtin_amdgcn_mfma_f32_16x16x32_bf16(aq[1][0], b0, z, 0,0,0);
            s1 = __builtin_amdgcn_mfma_f32_16x16x32_bf16(aq[1][1], b1, s1, 0,0,0);
            #pragma unroll
            for (int idx=0; idx<8; idx++){
                const int s2 = idx>>2, r = idx&3;
                float sc = (s2 ? s1[r] : s0[r]) * 0.125f;
                float x  = ((mw[idx] >> (h2*16 + lr)) & 1) ? sc : -INFINITY;
                float mo = m[idx];
                float mn = fmaxf(mo, x);
                float e  = __expf(fminf(mo, x) - mn);   // 1 exp per element
                bool gt  = x > mo;
                l[idx] = fmaf(l[idx], gt ? e : 1.f, gt ? 1.f : e);
                m[idx] = mn;
            }
        }
    }

    // reduce (m,l) across the 16 lanes sharing lg (partials over k mod 16)
    #pragma unroll
    for (int idx=0; idx<8; idx++){
        float mm = m[idx], ll = l[idx];
        #pragma unroll
        for (int off=1; off<16; off<<=1){
            float mo = __shfl_xor(mm, off, 64);
            float lo = __shfl_xor(ll, off, 64);
            float mn = fmaxf(mm, mo);
            ll = ll*__expf(mm-mn) + lo*__expf(mo-mn);
            mm = mn;
        }
        if (lr == 0){
            mstat[(size_t)bh*Ss + qv[idx]] = mm;
            lstat[(size_t)bh*Ss + qv[idx]] = ll;
        }
    }
}

// ---------------------------------------------------------------------------
// S2 fused: recompute scores (MFMA, bitwise-identical), normalize, write fp32
// weights (nontemporal stream), round P->bf16, LDS round-trip to A-frag
// layout, PV via MFMA against transposed V. Saves the 536 MB weights re-read.
// ---------------------------------------------------------------------------
__global__ __launch_bounds__(256) void attn_wpv(
    const u16* __restrict__ Q, const u16* __restrict__ K,
    const u16* __restrict__ Vt, const u32* __restrict__ mbits,
    const float* __restrict__ mstat, const float* __restrict__ lstat,
    float* __restrict__ wout, u16* __restrict__ attn)
{
    __shared__ __align__(16) u16 plds[4][32][40];   // per-wave P tile, padded
    const int t = threadIdx.x;
    const int lane = t & 63, wave = t >> 6;
    const int qt = blockIdx.x, bh = blockIdx.y;
    const int b = bh >> 4, h = bh & 15;
    const int qr0 = qt*128 + wave*32;
    const u16* qb  = Q  + ((size_t)bh*Ss + qr0)*DHh;
    const u16* kb  = K  + (size_t)bh*Ss*DHh;
    const u16* vtb = Vt + (size_t)bh*DHh*Ss;
    const u32* mb  = mbits + (size_t)b*Ss*(Ss/32);
    float* wop = wout + (size_t)bh*Ss*Ss;

    const int lr = lane & 15;
    const int lg = lane >> 4;

    short8 aq[2][2];
    #pragma unroll
    for (int s2=0;s2<2;s2++)
        #pragma unroll
        for (int dh=0; dh<2; dh++)
            aq[s2][dh] = *(const short8*)(qb + (size_t)(s2*16 + lr)*DHh + dh*32 + lg*8);

    int qv[8];
    float mrow[8], li[8];
    #pragma unroll
    for (int idx=0; idx<8; idx++){
        qv[idx] = qr0 + (idx>>2)*16 + lg*4 + (idx&3);
        mrow[idx] = mstat[(size_t)bh*Ss + qv[idx]];
        float lv  = lstat[(size_t)bh*Ss + qv[idx]];
        li[idx] = lv > 0.f ? 1.f/lv : 0.f;
    }

    f32x4 acc_o[2][4];
    #pragma unroll
    for (int s2=0;s2<2;s2++)
        #pragma unroll
        for (int dt=0;dt<4;dt++){
            f32x4 z = {0.f,0.f,0.f,0.f};
            acc_o[s2][dt] = z;
        }

    for (int k0=0; k0<Ss; k0+=32){
        u32 mw[8];
        #pragma unroll
        for (int idx=0; idx<8; idx++)
            mw[idx] = mb[(size_t)qv[idx]*(Ss/32) + (k0>>5)];
        #pragma unroll
        for (int h2=0; h2<2; h2++){
            const int kk = k0 + h2*16;
            const u16* kr = kb + (size_t)(kk + lr)*DHh + lg*8;
            short8 b0 = *(const short8*)kr;
            short8 b1 = *(const short8*)(kr + 32);
            f32x4 z = {0.f,0.f,0.f,0.f};
            f32x4 s0 = __builtin_amdgcn_mfma_f32_16x16x32_bf16(aq[0][0], b0, z, 0,0,0);
            s0 = __builtin_amdgcn_mfma_f32_16x16x32_bf16(aq[0][1], b1, s0, 0,0,0);
            f32x4 s1 = __builtin_amdgcn_mfma_f32_16x16x32_bf16(aq[1][0], b0, z, 0,0,0);
            s1 = __builtin_amdgcn_mfma_f32_16x16x32_bf16(aq[1][1], b1, s1, 0,0,0);
            #pragma unroll
            for (int idx=0; idx<8; idx++){
                const int s2 = idx>>2, r = idx&3;
                float sc  = (s2 ? s1[r] : s0[r]) * 0.125f;
                float wgt = ((mw[idx] >> (h2*16 + lr)) & 1)
                          ? __expf(sc - mrow[idx]) * li[idx] : 0.f;
                __builtin_nontemporal_store(wgt, wop + (size_t)qv[idx]*Ss + kk + lr);
                plds[wave][s2*16 + lg*4 + r][h2*16 + lr] = fb(wgt);
            }
        }
        // PV: A-frags from per-wave LDS tile (same wave: no barrier needed),
        // B-frags contiguous from transposed V.
        short8 pa0 = *(const short8*)&plds[wave][lr][lg*8];
        short8 pa1 = *(const short8*)&plds[wave][16 + lr][lg*8];
        #pragma unroll
        for (int dt=0; dt<4; dt++){
            short8 vb = *(const short8*)(vtb + (size_t)(dt*16 + lr)*Ss + k0 + lg*8);
            acc_o[0][dt] = __builtin_amdgcn_mfma_f32_16x16x32_bf16(pa0, vb, acc_o[0][dt], 0,0,0);
            acc_o[1][dt] = __builtin_amdgcn_mfma_f32_16x16x32_bf16(pa1, vb, acc_o[1][dt], 0,0,0);
        }
    }

    u16* ab = attn + (size_t)b*Ss*Dd + (size_t)h*DHh;
    #pragma unroll
    for (int s2=0;s2<2;s2++)
        #pragma unroll
        for (int dt=0;dt<4;dt++)
            #pragma unroll
            for (int r=0;r<4;r++){
                const int q = qr0 + s2*16 + lg*4 + r;
                ab[(size_t)q*Dd + dt*16 + lr] = fb(acc_o[s2][dt][r]);
            }
}

// ---------------------------------------------------------------------------
extern "C" void kernel_launch(void* const* d_in, const int* in_sizes, int n_in,
                              void* d_out, int out_size, void* d_ws, size_t ws_size,
                              hipStream_t stream) {
    const float* q      = (const float*)d_in[0];
    const float* k      = (const float*)d_in[1];
    const float* v      = (const float*)d_in[2];
    const int*   mask   = (const int*)d_in[3];
    const float* wq_w   = (const float*)d_in[4];
    const float* wq_b   = (const float*)d_in[5];
    const float* wk_w   = (const float*)d_in[6];
    const float* wk_b   = (const float*)d_in[7];
    const float* wv_w   = (const float*)d_in[8];
    const float* wv_b   = (const float*)d_in[9];
    const float* dense_w= (const float*)d_in[10];
    const float* dense_b= (const float*)d_in[11];

    float* out  = (float*)d_out;                    // [B,S,D] fp32
    float* wout = out + (size_t)Bb*Ss*Dd;           // [B,H,S,S] fp32

    // workspace: qs, ks [B,H,S,DH] bf16; vt [B,H,DH,S] bf16; attn [B,S,D] bf16;
    // mstat/lstat fp32; mbits [B,S,S/32] u32  (~35 MB total)
    u16* qs   = (u16*)d_ws;
    u16* ksb  = qs  + (size_t)Bb*Hh*Ss*DHh;
    u16* vt   = ksb + (size_t)Bb*Hh*Ss*DHh;
    u16* attn = vt  + (size_t)Bb*Hh*Ss*DHh;
    float* mstat = (float*)(attn + (size_t)Bb*Ss*Dd);
    float* lstat = mstat + (size_t)Bb*Hh*Ss;
    u32* mbits = (u32*)(lstat + (size_t)Bb*Hh*Ss);

    const int M = Bb*Ss, N = Dd, K = Dd;
    dim3 gg(M/128, N/128), bb(256);

    mask_pack<<<dim3((Bb*Ss*Ss/32)/256), bb, 0, stream>>>(mask, mbits);
    gemm_at<0,1><<<gg, bb, 0, stream>>>(q, wq_w, wq_b, qs,  M, N, K);
    gemm_at<0,1><<<gg, bb, 0, stream>>>(k, wk_w, wk_b, ksb, M, N, K);
    gemm_at<0,2><<<gg, bb, 0, stream>>>(v, wv_w, wv_b, vt,  M, N, K);

    dim3 ga(Ss/128, Bb*Hh);
    attn_stats_mfma<<<ga, bb, 0, stream>>>(qs, ksb, mbits, mstat, lstat);
    attn_wpv      <<<ga, bb, 0, stream>>>(qs, ksb, vt, mbits, mstat, lstat, wout, attn);

    gemm_at<1,0><<<gg, bb, 0, stream>>>(attn, dense_w, dense_b, out, M, N, K);
}

// Round 3
// 1224.860 us; speedup vs baseline: 1.6313x; 1.1497x over previous
//
#include <hip/hip_runtime.h>
#include <math.h>

// Problem constants (B=2, S=2048, D=1024, H=16, DH=64)
#define Bb 2
#define Ss 2048
#define Dd 1024
#define Hh 16
#define DHh 64

typedef unsigned short u16;
typedef unsigned int u32;
typedef __attribute__((ext_vector_type(8))) short short8;   // 8 bf16 = 4 VGPR
typedef __attribute__((ext_vector_type(4))) float f32x4;

__device__ __forceinline__ u16 fb(float f){
    u32 x = __float_as_uint(f);
    return (u16)((x + 0x7fffu + ((x>>16)&1u)) >> 16);   // RNE bf16
}
__device__ __forceinline__ float bf2f(u16 h){
    return __uint_as_float((u32)h << 16);
}
__device__ __forceinline__ u32 pack2(float a, float b){
    return (u32)fb(a) | ((u32)fb(b)<<16);
}
__device__ __forceinline__ void unpack8(uint4 v, float* f){
    f[0]=__uint_as_float(v.x<<16); f[1]=__uint_as_float(v.x&0xffff0000u);
    f[2]=__uint_as_float(v.y<<16); f[3]=__uint_as_float(v.y&0xffff0000u);
    f[4]=__uint_as_float(v.z<<16); f[5]=__uint_as_float(v.z&0xffff0000u);
    f[6]=__uint_as_float(v.w<<16); f[7]=__uint_as_float(v.w&0xffff0000u);
}

// ---------------------------------------------------------------------------
// fp32 -> (hi, lo) bf16 split: x = hi + lo + O(2^-18 x). 8 elems/thread.
// ---------------------------------------------------------------------------
__global__ __launch_bounds__(256) void split_hilo(
    const float* __restrict__ x, u16* __restrict__ hi, u16* __restrict__ lo,
    int n8)
{
    const int i = blockIdx.x*256 + threadIdx.x;
    if (i >= n8) return;
    float4 a = ((const float4*)x)[i*2];
    float4 b = ((const float4*)x)[i*2+1];
    float f[8] = {a.x,a.y,a.z,a.w,b.x,b.y,b.z,b.w};
    u16 h8[8], l8[8];
    #pragma unroll
    for (int j=0;j<8;j++){
        u16 h = fb(f[j]);
        h8[j] = h;
        l8[j] = fb(f[j] - bf2f(h));
    }
    *(uint4*)(hi + (size_t)i*8) = *(const uint4*)h8;
    *(uint4*)(lo + (size_t)i*8) = *(const uint4*)l8;
}

// ---------------------------------------------------------------------------
// MFMA GEMM: C[M,N] = sum_passes A_p @ W_p^T + bias, bf16 in, fp32 accum.
// NPASS=3: (A0,W0), (A0,W1), (A1,W0)   [hi/lo 3-term, fp32-faithful]
// NPASS=2: (A0,W0), (A0,W1)            [A already bf16-exact]
// MODE 0: fp32 row-major store (out).
// MODE 1: bf16 split-head store [B,H,S,DH].
// MODE 2: bf16 split-head transposed store [B,H,DH,S] (operand roles swapped
//         so the s-dim lands on lane&15 -> coalesced stores).
// Block 128x128 (4 waves x 64x64 wave-tiles), K-step 32, no LDS.
// mfma(P,Q): C row-dim (P row) = lg*4+r, col-dim (Q row) = lr  [verified r1].
// ---------------------------------------------------------------------------
template<int MODE, int NPASS>
__global__ __launch_bounds__(256) void gemm_mfma(
    const u16* __restrict__ A0, const u16* __restrict__ A1,
    const u16* __restrict__ W0, const u16* __restrict__ W1,
    const float* __restrict__ bias, void* __restrict__ outv,
    int M, int N, int K)
{
    const int t = threadIdx.x, lane = t & 63, wave = t >> 6;
    const int lr = lane & 15, lg = lane >> 4;
    const int bm = blockIdx.x, bn = blockIdx.y;
    const int wr = wave >> 1, wc = wave & 1;
    const int am0 = bm*128 + wr*64;      // A (m) base for this wave
    const int wn0 = bn*128 + wc*64;      // W (n) base for this wave

    f32x4 acc[4][4];
    #pragma unroll
    for (int i=0;i<4;i++)
        #pragma unroll
        for (int j=0;j<4;j++){ f32x4 z={0.f,0.f,0.f,0.f}; acc[i][j]=z; }

    for (int pass=0; pass<NPASS; pass++){
        const u16* Ap = (pass==2) ? A1 : A0;
        const u16* Wp = (pass==1) ? W1 : W0;
        const u16* Pb = (MODE==2) ? Wp + (size_t)(wn0 + lr)*K
                                  : Ap + (size_t)(am0 + lr)*K;
        const u16* Qb = (MODE==2) ? Ap + (size_t)(am0 + lr)*K
                                  : Wp + (size_t)(wn0 + lr)*K;
        for (int kt=0; kt<K; kt+=32){
            short8 pf[4], qf[4];
            #pragma unroll
            for (int i=0;i<4;i++){
                pf[i] = *(const short8*)(Pb + (size_t)(i*16)*K + kt + lg*8);
                qf[i] = *(const short8*)(Qb + (size_t)(i*16)*K + kt + lg*8);
            }
            #pragma unroll
            for (int i=0;i<4;i++)
                #pragma unroll
                for (int j=0;j<4;j++)
                    acc[i][j] = __builtin_amdgcn_mfma_f32_16x16x32_bf16(
                        pf[i], qf[j], acc[i][j], 0,0,0);
        }
    }

    if (MODE==0){
        float* op = (float*)outv;
        float bq[4];
        #pragma unroll
        for (int j=0;j<4;j++) bq[j] = bias[wn0 + j*16 + lr];
        #pragma unroll
        for (int i=0;i<4;i++)
            #pragma unroll
            for (int r=0;r<4;r++){
                const int m = am0 + i*16 + lg*4 + r;
                #pragma unroll
                for (int j=0;j<4;j++)
                    op[(size_t)m*N + wn0 + j*16 + lr] = acc[i][j][r] + bq[j];
            }
    } else if (MODE==1){
        u16* op = (u16*)outv;
        float bq[4];
        #pragma unroll
        for (int j=0;j<4;j++) bq[j] = bias[wn0 + j*16 + lr];
        #pragma unroll
        for (int i=0;i<4;i++)
            #pragma unroll
            for (int r=0;r<4;r++){
                const int m = am0 + i*16 + lg*4 + r;
                const int b = m >> 11, s = m & (Ss-1);
                #pragma unroll
                for (int j=0;j<4;j++){
                    const int n = wn0 + j*16 + lr;
                    const int h = n >> 6, d = n & (DHh-1);
                    op[((size_t)((b*Hh + h)*Ss + s))*DHh + d] =
                        fb(acc[i][j][r] + bq[j]);
                }
            }
    } else {
        // MODE 2: P=W (n-dim on i, lg*4+r), Q=A (m-dim on j, lr)
        u16* op = (u16*)outv;
        float bp[4][4];
        #pragma unroll
        for (int i=0;i<4;i++){
            float4 bv = *(const float4*)(bias + wn0 + i*16 + lg*4);
            bp[i][0]=bv.x; bp[i][1]=bv.y; bp[i][2]=bv.z; bp[i][3]=bv.w;
        }
        #pragma unroll
        for (int i=0;i<4;i++)
            #pragma unroll
            for (int r=0;r<4;r++){
                const int n = wn0 + i*16 + lg*4 + r;
                const int h = n >> 6, d = n & (DHh-1);
                #pragma unroll
                for (int j=0;j<4;j++){
                    const int m = am0 + j*16 + lr;
                    const int b = m >> 11, s = m & (Ss-1);
                    op[((size_t)((b*Hh + h)*DHh + d))*Ss + s] =
                        fb(acc[i][j][r] + bp[i][r]);
                }
            }
    }
}

// ---------------------------------------------------------------------------
// mask [B,1,S,S] int32 -> bitmask [B,S,S/32]
// ---------------------------------------------------------------------------
__global__ __launch_bounds__(256) void mask_pack(
    const int* __restrict__ mask, u32* __restrict__ mbits)
{
    const size_t w = (size_t)blockIdx.x*256 + threadIdx.x;
    const int* p = mask + w*32;
    u32 bits = 0;
    #pragma unroll
    for (int i=0;i<32;i+=4){
        int4 v = *(const int4*)(p + i);
        bits |= (u32)(v.x!=0) << i;
        bits |= (u32)(v.y!=0) << (i+1);
        bits |= (u32)(v.z!=0) << (i+2);
        bits |= (u32)(v.w!=0) << (i+3);
    }
    mbits[w] = bits;
}

// ---------------------------------------------------------------------------
// S1: per-row softmax stats (m, l) via MFMA QK^T. No LDS.
// ---------------------------------------------------------------------------
__global__ __launch_bounds__(256) void attn_stats_mfma(
    const u16* __restrict__ Q, const u16* __restrict__ K,
    const u32* __restrict__ mbits,
    float* __restrict__ mstat, float* __restrict__ lstat)
{
    const int t = threadIdx.x;
    const int lane = t & 63, wave = t >> 6;
    const int qt = blockIdx.x, bh = blockIdx.y;
    const int b = bh >> 4;
    const int qr0 = qt*128 + wave*32;
    const u16* qb = Q + ((size_t)bh*Ss + qr0)*DHh;
    const u16* kb = K + (size_t)bh*Ss*DHh;
    const u32* mb = mbits + (size_t)b*Ss*(Ss/32);

    const int lr = lane & 15;
    const int lg = lane >> 4;

    short8 aq[2][2];
    #pragma unroll
    for (int s2=0;s2<2;s2++)
        #pragma unroll
        for (int dh=0; dh<2; dh++)
            aq[s2][dh] = *(const short8*)(qb + (size_t)(s2*16 + lr)*DHh + dh*32 + lg*8);

    int qv[8];
    #pragma unroll
    for (int idx=0; idx<8; idx++)
        qv[idx] = qr0 + (idx>>2)*16 + lg*4 + (idx&3);

    float m[8], l[8];
    #pragma unroll
    for (int i=0;i<8;i++){ m[i]=-1e30f; l[i]=0.f; }

    for (int k0=0; k0<Ss; k0+=32){
        u32 mw[8];
        #pragma unroll
        for (int idx=0; idx<8; idx++)
            mw[idx] = mb[(size_t)qv[idx]*(Ss/32) + (k0>>5)];
        #pragma unroll
        for (int h2=0; h2<2; h2++){
            const u16* kr = kb + (size_t)(k0 + h2*16 + lr)*DHh + lg*8;
            short8 b0 = *(const short8*)kr;
            short8 b1 = *(const short8*)(kr + 32);
            f32x4 z = {0.f,0.f,0.f,0.f};
            f32x4 s0 = __builtin_amdgcn_mfma_f32_16x16x32_bf16(aq[0][0], b0, z, 0,0,0);
            s0 = __builtin_amdgcn_mfma_f32_16x16x32_bf16(aq[0][1], b1, s0, 0,0,0);
            f32x4 s1 = __builtin_amdgcn_mfma_f32_16x16x32_bf16(aq[1][0], b0, z, 0,0,0);
            s1 = __builtin_amdgcn_mfma_f32_16x16x32_bf16(aq[1][1], b1, s1, 0,0,0);
            #pragma unroll
            for (int idx=0; idx<8; idx++){
                const int s2 = idx>>2, r = idx&3;
                float sc = (s2 ? s1[r] : s0[r]) * 0.125f;
                float x  = ((mw[idx] >> (h2*16 + lr)) & 1) ? sc : -INFINITY;
                float mo = m[idx];
                float mn = fmaxf(mo, x);
                float e  = __expf(fminf(mo, x) - mn);
                bool gt  = x > mo;
                l[idx] = fmaf(l[idx], gt ? e : 1.f, gt ? 1.f : e);
                m[idx] = mn;
            }
        }
    }

    #pragma unroll
    for (int idx=0; idx<8; idx++){
        float mm = m[idx], ll = l[idx];
        #pragma unroll
        for (int off=1; off<16; off<<=1){
            float mo = __shfl_xor(mm, off, 64);
            float lo = __shfl_xor(ll, off, 64);
            float mn = fmaxf(mm, mo);
            ll = ll*__expf(mm-mn) + lo*__expf(mo-mn);
            mm = mn;
        }
        if (lr == 0){
            mstat[(size_t)bh*Ss + qv[idx]] = mm;
            lstat[(size_t)bh*Ss + qv[idx]] = ll;
        }
    }
}

// ---------------------------------------------------------------------------
// S2 fused: recompute scores, normalize, stream fp32 weights, PV via MFMA.
// ---------------------------------------------------------------------------
__global__ __launch_bounds__(256) void attn_wpv(
    const u16* __restrict__ Q, const u16* __restrict__ K,
    const u16* __restrict__ Vt, const u32* __restrict__ mbits,
    const float* __restrict__ mstat, const float* __restrict__ lstat,
    float* __restrict__ wout, u16* __restrict__ attn)
{
    __shared__ __align__(16) u16 plds[4][32][40];
    const int t = threadIdx.x;
    const int lane = t & 63, wave = t >> 6;
    const int qt = blockIdx.x, bh = blockIdx.y;
    const int b = bh >> 4, h = bh & 15;
    const int qr0 = qt*128 + wave*32;
    const u16* qb  = Q  + ((size_t)bh*Ss + qr0)*DHh;
    const u16* kb  = K  + (size_t)bh*Ss*DHh;
    const u16* vtb = Vt + (size_t)bh*DHh*Ss;
    const u32* mb  = mbits + (size_t)b*Ss*(Ss/32);
    float* wop = wout + (size_t)bh*Ss*Ss;

    const int lr = lane & 15;
    const int lg = lane >> 4;

    short8 aq[2][2];
    #pragma unroll
    for (int s2=0;s2<2;s2++)
        #pragma unroll
        for (int dh=0; dh<2; dh++)
            aq[s2][dh] = *(const short8*)(qb + (size_t)(s2*16 + lr)*DHh + dh*32 + lg*8);

    int qv[8];
    float mrow[8], li[8];
    #pragma unroll
    for (int idx=0; idx<8; idx++){
        qv[idx] = qr0 + (idx>>2)*16 + lg*4 + (idx&3);
        mrow[idx] = mstat[(size_t)bh*Ss + qv[idx]];
        float lv  = lstat[(size_t)bh*Ss + qv[idx]];
        li[idx] = lv > 0.f ? 1.f/lv : 0.f;
    }

    f32x4 acc_o[2][4];
    #pragma unroll
    for (int s2=0;s2<2;s2++)
        #pragma unroll
        for (int dt=0;dt<4;dt++){
            f32x4 z = {0.f,0.f,0.f,0.f};
            acc_o[s2][dt] = z;
        }

    for (int k0=0; k0<Ss; k0+=32){
        u32 mw[8];
        #pragma unroll
        for (int idx=0; idx<8; idx++)
            mw[idx] = mb[(size_t)qv[idx]*(Ss/32) + (k0>>5)];
        #pragma unroll
        for (int h2=0; h2<2; h2++){
            const int kk = k0 + h2*16;
            const u16* kr = kb + (size_t)(kk + lr)*DHh + lg*8;
            short8 b0 = *(const short8*)kr;
            short8 b1 = *(const short8*)(kr + 32);
            f32x4 z = {0.f,0.f,0.f,0.f};
            f32x4 s0 = __builtin_amdgcn_mfma_f32_16x16x32_bf16(aq[0][0], b0, z, 0,0,0);
            s0 = __builtin_amdgcn_mfma_f32_16x16x32_bf16(aq[0][1], b1, s0, 0,0,0);
            f32x4 s1 = __builtin_amdgcn_mfma_f32_16x16x32_bf16(aq[1][0], b0, z, 0,0,0);
            s1 = __builtin_amdgcn_mfma_f32_16x16x32_bf16(aq[1][1], b1, s1, 0,0,0);
            #pragma unroll
            for (int idx=0; idx<8; idx++){
                const int s2 = idx>>2, r = idx&3;
                float sc  = (s2 ? s1[r] : s0[r]) * 0.125f;
                float wgt = ((mw[idx] >> (h2*16 + lr)) & 1)
                          ? __expf(sc - mrow[idx]) * li[idx] : 0.f;
                __builtin_nontemporal_store(wgt, wop + (size_t)qv[idx]*Ss + kk + lr);
                plds[wave][s2*16 + lg*4 + r][h2*16 + lr] = fb(wgt);
            }
        }
        short8 pa0 = *(const short8*)&plds[wave][lr][lg*8];
        short8 pa1 = *(const short8*)&plds[wave][16 + lr][lg*8];
        #pragma unroll
        for (int dt=0; dt<4; dt++){
            short8 vb = *(const short8*)(vtb + (size_t)(dt*16 + lr)*Ss + k0 + lg*8);
            acc_o[0][dt] = __builtin_amdgcn_mfma_f32_16x16x32_bf16(pa0, vb, acc_o[0][dt], 0,0,0);
            acc_o[1][dt] = __builtin_amdgcn_mfma_f32_16x16x32_bf16(pa1, vb, acc_o[1][dt], 0,0,0);
        }
    }

    u16* ab = attn + (size_t)b*Ss*Dd + (size_t)h*DHh;
    #pragma unroll
    for (int s2=0;s2<2;s2++)
        #pragma unroll
        for (int dt=0;dt<4;dt++)
            #pragma unroll
            for (int r=0;r<4;r++){
                const int q = qr0 + s2*16 + lg*4 + r;
                ab[(size_t)q*Dd + dt*16 + lr] = fb(acc_o[s2][dt][r]);
            }
}

// ---------------------------------------------------------------------------
extern "C" void kernel_launch(void* const* d_in, const int* in_sizes, int n_in,
                              void* d_out, int out_size, void* d_ws, size_t ws_size,
                              hipStream_t stream) {
    const float* q      = (const float*)d_in[0];
    const float* k      = (const float*)d_in[1];
    const float* v      = (const float*)d_in[2];
    const int*   mask   = (const int*)d_in[3];
    const float* wq_w   = (const float*)d_in[4];
    const float* wq_b   = (const float*)d_in[5];
    const float* wk_w   = (const float*)d_in[6];
    const float* wk_b   = (const float*)d_in[7];
    const float* wv_w   = (const float*)d_in[8];
    const float* wv_b   = (const float*)d_in[9];
    const float* dense_w= (const float*)d_in[10];
    const float* dense_b= (const float*)d_in[11];

    float* out  = (float*)d_out;                    // [B,S,D] fp32
    float* wout = out + (size_t)Bb*Ss*Dd;           // [B,H,S,S] fp32

    // d_ws layout: 33.5 MB (identical footprint to the passing round-1 run)
    u16* qs   = (u16*)d_ws;                         // [B,H,S,DH] 8 MB
    u16* ksb  = qs  + (size_t)Bb*Hh*Ss*DHh;         // 8 MB
    u16* vt   = ksb + (size_t)Bb*Hh*Ss*DHh;         // [B,H,DH,S] 8 MB
    u16* attn = vt  + (size_t)Bb*Hh*Ss*DHh;         // [B,S,D] 8 MB
    float* mstat = (float*)(attn + (size_t)Bb*Ss*Dd);
    float* lstat = mstat + (size_t)Bb*Hh*Ss;
    u32* mbits = (u32*)(lstat + (size_t)Bb*Hh*Ss);  // 1 MB

    // Split scratch lives in the d_out weights region (537 MB): dead until
    // attn_wpv overwrites every element of wout AFTER the projections.
    u16* Ahi = (u16*)wout;                          // [B*S, D] 8 MB
    u16* Alo = Ahi + (size_t)Bb*Ss*Dd;              // 8 MB
    u16* Whi = Alo + (size_t)Bb*Ss*Dd;              // [D, D] 2 MB
    u16* Wlo = Whi + (size_t)Dd*Dd;                 // 2 MB
    // Dense-W split (needed AFTER attn_wpv) reuses the then-dead qs buffer.
    u16* Whi2 = qs;
    u16* Wlo2 = qs + (size_t)Dd*Dd;

    const int M = Bb*Ss, N = Dd, K = Dd;
    const int n8_in = M*K/8, n8_w = N*K/8;
    dim3 gg(M/128, N/128), bb(256);

    mask_pack<<<dim3((Bb*Ss*Ss/32)/256), bb, 0, stream>>>(mask, mbits);

    // Q projection
    split_hilo<<<dim3((n8_in+255)/256), bb, 0, stream>>>(q, Ahi, Alo, n8_in);
    split_hilo<<<dim3((n8_w+255)/256),  bb, 0, stream>>>(wq_w, Whi, Wlo, n8_w);
    gemm_mfma<1,3><<<gg, bb, 0, stream>>>(Ahi, Alo, Whi, Wlo, wq_b, qs, M, N, K);
    // K projection
    split_hilo<<<dim3((n8_in+255)/256), bb, 0, stream>>>(k, Ahi, Alo, n8_in);
    split_hilo<<<dim3((n8_w+255)/256),  bb, 0, stream>>>(wk_w, Whi, Wlo, n8_w);
    gemm_mfma<1,3><<<gg, bb, 0, stream>>>(Ahi, Alo, Whi, Wlo, wk_b, ksb, M, N, K);
    // V projection (transposed store)
    split_hilo<<<dim3((n8_in+255)/256), bb, 0, stream>>>(v, Ahi, Alo, n8_in);
    split_hilo<<<dim3((n8_w+255)/256),  bb, 0, stream>>>(wv_w, Whi, Wlo, n8_w);
    gemm_mfma<2,3><<<gg, bb, 0, stream>>>(Ahi, Alo, Whi, Wlo, wv_b, vt, M, N, K);

    dim3 ga(Ss/128, Bb*Hh);
    attn_stats_mfma<<<ga, bb, 0, stream>>>(qs, ksb, mbits, mstat, lstat);
    attn_wpv      <<<ga, bb, 0, stream>>>(qs, ksb, vt, mbits, mstat, lstat, wout, attn);

    // Dense projection: A = attn (bf16-exact), W split 2-term; qs is dead now.
    split_hilo<<<dim3((n8_w+255)/256), bb, 0, stream>>>(dense_w, Whi2, Wlo2, n8_w);
    gemm_mfma<0,2><<<gg, bb, 0, stream>>>(attn, attn, Whi2, Wlo2, dense_b, out, M, N, K);
}

// Round 4
// 1113.847 us; speedup vs baseline: 1.7938x; 1.0997x over previous
//
#include <hip/hip_runtime.h>
#include <math.h>

// Problem constants (B=2, S=2048, D=1024, H=16, DH=64)
#define Bb 2
#define Ss 2048
#define Dd 1024
#define Hh 16
#define DHh 64

typedef unsigned short u16;
typedef unsigned int u32;
typedef __attribute__((ext_vector_type(8))) short short8;   // 8 bf16 = 4 VGPR
typedef __attribute__((ext_vector_type(4))) float f32x4;

#define LOG2E 1.44269504088896340736f

__device__ __forceinline__ u16 fb(float f){
    u32 x = __float_as_uint(f);
    return (u16)((x + 0x7fffu + ((x>>16)&1u)) >> 16);   // RNE bf16
}
__device__ __forceinline__ float bf2f(u16 h){
    return __uint_as_float((u32)h << 16);
}

// ---------------------------------------------------------------------------
// fp32 -> (hi, lo) bf16 split: x = hi + lo + O(2^-18 x). 8 elems/thread.
// ---------------------------------------------------------------------------
__global__ __launch_bounds__(256) void split_hilo(
    const float* __restrict__ x, u16* __restrict__ hi, u16* __restrict__ lo,
    int n8)
{
    const int i = blockIdx.x*256 + threadIdx.x;
    if (i >= n8) return;
    float4 a = ((const float4*)x)[i*2];
    float4 b = ((const float4*)x)[i*2+1];
    float f[8] = {a.x,a.y,a.z,a.w,b.x,b.y,b.z,b.w};
    u16 h8[8], l8[8];
    #pragma unroll
    for (int j=0;j<8;j++){
        u16 h = fb(f[j]);
        h8[j] = h;
        l8[j] = fb(f[j] - bf2f(h));
    }
    *(uint4*)(hi + (size_t)i*8) = *(const uint4*)h8;
    *(uint4*)(lo + (size_t)i*8) = *(const uint4*)l8;
}

// ---------------------------------------------------------------------------
// Fused MFMA GEMM: C = A0@W0^T + A0@W1^T [+ A1@W0^T] + bias, single K-loop.
// NTERM=3: hi/lo 3-term (fp32-faithful); NTERM=2: A exact, W split 2-term.
// MODE 0: fp32 row-major store. MODE 1: bf16 split-head [B,H,S,DH].
// MODE 2: bf16 split-head transposed [B,H,DH,S] (P/Q operand roles swapped
//         so the s-dim lands on lane&15 -> coalesced stores).
// Term set {(p0,q0),(p0,q1),(p1,q0)} is symmetric under the MODE-2 swap.
// Block 128x128 (4 waves x 64x64), K-step 32, no LDS.
// mfma(P,Q): C row-dim (P row) = lg*4+r, col-dim (Q row) = lr  [verified r1].
// ---------------------------------------------------------------------------
template<int MODE, int NTERM>
__global__ __launch_bounds__(256) void gemm_fused(
    const u16* __restrict__ A0, const u16* __restrict__ A1,
    const u16* __restrict__ W0, const u16* __restrict__ W1,
    const float* __restrict__ bias, void* __restrict__ outv,
    int M, int N, int K)
{
    const int t = threadIdx.x, lane = t & 63, wave = t >> 6;
    const int lr = lane & 15, lg = lane >> 4;
    const int bm = blockIdx.x, bn = blockIdx.y;
    const int wr = wave >> 1, wc = wave & 1;
    const int am0 = bm*128 + wr*64;      // A (m) base for this wave
    const int wn0 = bn*128 + wc*64;      // W (n) base for this wave

    const u16* P0 = (MODE==2) ? W0 : A0;
    const u16* P1 = (MODE==2) ? W1 : A1;
    const u16* Q0 = (MODE==2) ? A0 : W0;
    const u16* Q1 = (MODE==2) ? A1 : W1;
    const int pr0 = (MODE==2) ? wn0 : am0;
    const int qr0_ = (MODE==2) ? am0 : wn0;
    const u16* Pb0 = P0 + (size_t)(pr0 + lr)*K + lg*8;
    const u16* Pb1 = P1 + (size_t)(pr0 + lr)*K + lg*8;
    const u16* Qb0 = Q0 + (size_t)(qr0_ + lr)*K + lg*8;
    const u16* Qb1 = Q1 + (size_t)(qr0_ + lr)*K + lg*8;

    f32x4 acc[4][4];
    #pragma unroll
    for (int i=0;i<4;i++)
        #pragma unroll
        for (int j=0;j<4;j++){ f32x4 z={0.f,0.f,0.f,0.f}; acc[i][j]=z; }

    for (int kt=0; kt<K; kt+=32){
        short8 pf0[4], pf1[4], qf0[4], qf1[4];
        #pragma unroll
        for (int i=0;i<4;i++){
            pf0[i] = *(const short8*)(Pb0 + (size_t)(i*16)*K + kt);
            qf0[i] = *(const short8*)(Qb0 + (size_t)(i*16)*K + kt);
            qf1[i] = *(const short8*)(Qb1 + (size_t)(i*16)*K + kt);
            if (NTERM==3)
                pf1[i] = *(const short8*)(Pb1 + (size_t)(i*16)*K + kt);
        }
        #pragma unroll
        for (int i=0;i<4;i++)
            #pragma unroll
            for (int j=0;j<4;j++){
                acc[i][j] = __builtin_amdgcn_mfma_f32_16x16x32_bf16(
                    pf0[i], qf0[j], acc[i][j], 0,0,0);
                acc[i][j] = __builtin_amdgcn_mfma_f32_16x16x32_bf16(
                    pf0[i], qf1[j], acc[i][j], 0,0,0);
                if (NTERM==3)
                    acc[i][j] = __builtin_amdgcn_mfma_f32_16x16x32_bf16(
                        pf1[i], qf0[j], acc[i][j], 0,0,0);
            }
    }

    if (MODE==0){
        float* op = (float*)outv;
        float bq[4];
        #pragma unroll
        for (int j=0;j<4;j++) bq[j] = bias[wn0 + j*16 + lr];
        #pragma unroll
        for (int i=0;i<4;i++)
            #pragma unroll
            for (int r=0;r<4;r++){
                const int m = am0 + i*16 + lg*4 + r;
                #pragma unroll
                for (int j=0;j<4;j++)
                    op[(size_t)m*N + wn0 + j*16 + lr] = acc[i][j][r] + bq[j];
            }
    } else if (MODE==1){
        u16* op = (u16*)outv;
        float bq[4];
        #pragma unroll
        for (int j=0;j<4;j++) bq[j] = bias[wn0 + j*16 + lr];
        #pragma unroll
        for (int i=0;i<4;i++)
            #pragma unroll
            for (int r=0;r<4;r++){
                const int m = am0 + i*16 + lg*4 + r;
                const int b = m >> 11, s = m & (Ss-1);
                #pragma unroll
                for (int j=0;j<4;j++){
                    const int n = wn0 + j*16 + lr;
                    const int h = n >> 6, d = n & (DHh-1);
                    op[((size_t)((b*Hh + h)*Ss + s))*DHh + d] =
                        fb(acc[i][j][r] + bq[j]);
                }
            }
    } else {
        // MODE 2: P=W (n-dim on i, lg*4+r), Q=A (m-dim on j, lr)
        u16* op = (u16*)outv;
        float bp[4][4];
        #pragma unroll
        for (int i=0;i<4;i++){
            float4 bv = *(const float4*)(bias + wn0 + i*16 + lg*4);
            bp[i][0]=bv.x; bp[i][1]=bv.y; bp[i][2]=bv.z; bp[i][3]=bv.w;
        }
        #pragma unroll
        for (int i=0;i<4;i++)
            #pragma unroll
            for (int r=0;r<4;r++){
                const int n = wn0 + i*16 + lg*4 + r;
                const int h = n >> 6, d = n & (DHh-1);
                #pragma unroll
                for (int j=0;j<4;j++){
                    const int m = am0 + j*16 + lr;
                    const int b = m >> 11, s = m & (Ss-1);
                    op[((size_t)((b*Hh + h)*DHh + d))*Ss + s] =
                        fb(acc[i][j][r] + bp[i][r]);
                }
            }
    }
}

// ---------------------------------------------------------------------------
// mask [B,1,S,S] int32 -> bitmask [B,S,S/32]
// ---------------------------------------------------------------------------
__global__ __launch_bounds__(256) void mask_pack(
    const int* __restrict__ mask, u32* __restrict__ mbits)
{
    const size_t w = (size_t)blockIdx.x*256 + threadIdx.x;
    const int* p = mask + w*32;
    u32 bits = 0;
    #pragma unroll
    for (int i=0;i<32;i+=4){
        int4 v = *(const int4*)(p + i);
        bits |= (u32)(v.x!=0) << i;
        bits |= (u32)(v.y!=0) << (i+1);
        bits |= (u32)(v.z!=0) << (i+2);
        bits |= (u32)(v.w!=0) << (i+3);
    }
    mbits[w] = bits;
}

// ---------------------------------------------------------------------------
// S1: per-row softmax stats (m, l) via MFMA QK^T. No LDS.
// Stats kept in log2 domain: s2 = s*0.125*log2e; l = sum 2^(s2-m2) == sum
// exp(s-m). Saves one mul per score (exp2 is the native HW op).
// ---------------------------------------------------------------------------
__global__ __launch_bounds__(256) void attn_stats_mfma(
    const u16* __restrict__ Q, const u16* __restrict__ K,
    const u32* __restrict__ mbits,
    float* __restrict__ mstat, float* __restrict__ lstat)
{
    const int t = threadIdx.x;
    const int lane = t & 63, wave = t >> 6;
    const int qt = blockIdx.x, bh = blockIdx.y;
    const int b = bh >> 4;
    const int qr0 = qt*128 + wave*32;
    const u16* qb = Q + ((size_t)bh*Ss + qr0)*DHh;
    const u16* kb = K + (size_t)bh*Ss*DHh;
    const u32* mb = mbits + (size_t)b*Ss*(Ss/32);

    const int lr = lane & 15;
    const int lg = lane >> 4;

    short8 aq[2][2];
    #pragma unroll
    for (int s2=0;s2<2;s2++)
        #pragma unroll
        for (int dh=0; dh<2; dh++)
            aq[s2][dh] = *(const short8*)(qb + (size_t)(s2*16 + lr)*DHh + dh*32 + lg*8);

    int qv[8];
    #pragma unroll
    for (int idx=0; idx<8; idx++)
        qv[idx] = qr0 + (idx>>2)*16 + lg*4 + (idx&3);

    float m[8], l[8];
    #pragma unroll
    for (int i=0;i<8;i++){ m[i]=-1e30f; l[i]=0.f; }

    const float SC = 0.125f * LOG2E;

    for (int k0=0; k0<Ss; k0+=32){
        u32 mw[8];
        #pragma unroll
        for (int idx=0; idx<8; idx++)
            mw[idx] = mb[(size_t)qv[idx]*(Ss/32) + (k0>>5)];
        #pragma unroll
        for (int h2=0; h2<2; h2++){
            const u16* kr = kb + (size_t)(k0 + h2*16 + lr)*DHh + lg*8;
            short8 b0 = *(const short8*)kr;
            short8 b1 = *(const short8*)(kr + 32);
            f32x4 z = {0.f,0.f,0.f,0.f};
            f32x4 s0 = __builtin_amdgcn_mfma_f32_16x16x32_bf16(aq[0][0], b0, z, 0,0,0);
            s0 = __builtin_amdgcn_mfma_f32_16x16x32_bf16(aq[0][1], b1, s0, 0,0,0);
            f32x4 s1 = __builtin_amdgcn_mfma_f32_16x16x32_bf16(aq[1][0], b0, z, 0,0,0);
            s1 = __builtin_amdgcn_mfma_f32_16x16x32_bf16(aq[1][1], b1, s1, 0,0,0);
            #pragma unroll
            for (int idx=0; idx<8; idx++){
                const int s2 = idx>>2, r = idx&3;
                float sc = (s2 ? s1[r] : s0[r]) * SC;
                float x  = ((mw[idx] >> (h2*16 + lr)) & 1) ? sc : -INFINITY;
                float mo = m[idx];
                float mn = fmaxf(mo, x);
                float e  = exp2f(fminf(mo, x) - mn);   // 1 exp2 per element
                bool gt  = x > mo;
                l[idx] = fmaf(l[idx], gt ? e : 1.f, gt ? 1.f : e);
                m[idx] = mn;
            }
        }
    }

    #pragma unroll
    for (int idx=0; idx<8; idx++){
        float mm = m[idx], ll = l[idx];
        #pragma unroll
        for (int off=1; off<16; off<<=1){
            float mo = __shfl_xor(mm, off, 64);
            float lo = __shfl_xor(ll, off, 64);
            float mn = fmaxf(mm, mo);
            ll = ll*exp2f(mm-mn) + lo*exp2f(mo-mn);
            mm = mn;
        }
        if (lr == 0){
            mstat[(size_t)bh*Ss + qv[idx]] = mm;   // log2 domain
            lstat[(size_t)bh*Ss + qv[idx]] = ll;
        }
    }
}

// ---------------------------------------------------------------------------
// S2 fused: recompute scores, normalize (log2 domain), stream fp32 weights,
// PV via MFMA against transposed V.
// ---------------------------------------------------------------------------
__global__ __launch_bounds__(256) void attn_wpv(
    const u16* __restrict__ Q, const u16* __restrict__ K,
    const u16* __restrict__ Vt, const u32* __restrict__ mbits,
    const float* __restrict__ mstat, const float* __restrict__ lstat,
    float* __restrict__ wout, u16* __restrict__ attn)
{
    __shared__ __align__(16) u16 plds[4][32][40];
    const int t = threadIdx.x;
    const int lane = t & 63, wave = t >> 6;
    const int qt = blockIdx.x, bh = blockIdx.y;
    const int b = bh >> 4, h = bh & 15;
    const int qr0 = qt*128 + wave*32;
    const u16* qb  = Q  + ((size_t)bh*Ss + qr0)*DHh;
    const u16* kb  = K  + (size_t)bh*Ss*DHh;
    const u16* vtb = Vt + (size_t)bh*DHh*Ss;
    const u32* mb  = mbits + (size_t)b*Ss*(Ss/32);
    float* wop = wout + (size_t)bh*Ss*Ss;

    const int lr = lane & 15;
    const int lg = lane >> 4;

    short8 aq[2][2];
    #pragma unroll
    for (int s2=0;s2<2;s2++)
        #pragma unroll
        for (int dh=0; dh<2; dh++)
            aq[s2][dh] = *(const short8*)(qb + (size_t)(s2*16 + lr)*DHh + dh*32 + lg*8);

    int qv[8];
    float mrow[8], li[8];
    #pragma unroll
    for (int idx=0; idx<8; idx++){
        qv[idx] = qr0 + (idx>>2)*16 + lg*4 + (idx&3);
        mrow[idx] = mstat[(size_t)bh*Ss + qv[idx]];   // log2 domain
        float lv  = lstat[(size_t)bh*Ss + qv[idx]];
        li[idx] = lv > 0.f ? 1.f/lv : 0.f;
    }

    f32x4 acc_o[2][4];
    #pragma unroll
    for (int s2=0;s2<2;s2++)
        #pragma unroll
        for (int dt=0;dt<4;dt++){
            f32x4 z = {0.f,0.f,0.f,0.f};
            acc_o[s2][dt] = z;
        }

    const float SC = 0.125f * LOG2E;

    for (int k0=0; k0<Ss; k0+=32){
        u32 mw[8];
        #pragma unroll
        for (int idx=0; idx<8; idx++)
            mw[idx] = mb[(size_t)qv[idx]*(Ss/32) + (k0>>5)];
        #pragma unroll
        for (int h2=0; h2<2; h2++){
            const int kk = k0 + h2*16;
            const u16* kr = kb + (size_t)(kk + lr)*DHh + lg*8;
            short8 b0 = *(const short8*)kr;
            short8 b1 = *(const short8*)(kr + 32);
            f32x4 z = {0.f,0.f,0.f,0.f};
            f32x4 s0 = __builtin_amdgcn_mfma_f32_16x16x32_bf16(aq[0][0], b0, z, 0,0,0);
            s0 = __builtin_amdgcn_mfma_f32_16x16x32_bf16(aq[0][1], b1, s0, 0,0,0);
            f32x4 s1 = __builtin_amdgcn_mfma_f32_16x16x32_bf16(aq[1][0], b0, z, 0,0,0);
            s1 = __builtin_amdgcn_mfma_f32_16x16x32_bf16(aq[1][1], b1, s1, 0,0,0);
            #pragma unroll
            for (int idx=0; idx<8; idx++){
                const int s2 = idx>>2, r = idx&3;
                float sc  = (s2 ? s1[r] : s0[r]) * SC;
                float wgt = ((mw[idx] >> (h2*16 + lr)) & 1)
                          ? exp2f(sc - mrow[idx]) * li[idx] : 0.f;
                __builtin_nontemporal_store(wgt, wop + (size_t)qv[idx]*Ss + kk + lr);
                plds[wave][s2*16 + lg*4 + r][h2*16 + lr] = fb(wgt);
            }
        }
        short8 pa0 = *(const short8*)&plds[wave][lr][lg*8];
        short8 pa1 = *(const short8*)&plds[wave][16 + lr][lg*8];
        #pragma unroll
        for (int dt=0; dt<4; dt++){
            short8 vb = *(const short8*)(vtb + (size_t)(dt*16 + lr)*Ss + k0 + lg*8);
            acc_o[0][dt] = __builtin_amdgcn_mfma_f32_16x16x32_bf16(pa0, vb, acc_o[0][dt], 0,0,0);
            acc_o[1][dt] = __builtin_amdgcn_mfma_f32_16x16x32_bf16(pa1, vb, acc_o[1][dt], 0,0,0);
        }
    }

    u16* ab = attn + (size_t)b*Ss*Dd + (size_t)h*DHh;
    #pragma unroll
    for (int s2=0;s2<2;s2++)
        #pragma unroll
        for (int dt=0;dt<4;dt++)
            #pragma unroll
            for (int r=0;r<4;r++){
                const int q = qr0 + s2*16 + lg*4 + r;
                ab[(size_t)q*Dd + dt*16 + lr] = fb(acc_o[s2][dt][r]);
            }
}

// ---------------------------------------------------------------------------
extern "C" void kernel_launch(void* const* d_in, const int* in_sizes, int n_in,
                              void* d_out, int out_size, void* d_ws, size_t ws_size,
                              hipStream_t stream) {
    const float* q      = (const float*)d_in[0];
    const float* k      = (const float*)d_in[1];
    const float* v      = (const float*)d_in[2];
    const int*   mask   = (const int*)d_in[3];
    const float* wq_w   = (const float*)d_in[4];
    const float* wq_b   = (const float*)d_in[5];
    const float* wk_w   = (const float*)d_in[6];
    const float* wk_b   = (const float*)d_in[7];
    const float* wv_w   = (const float*)d_in[8];
    const float* wv_b   = (const float*)d_in[9];
    const float* dense_w= (const float*)d_in[10];
    const float* dense_b= (const float*)d_in[11];

    float* out  = (float*)d_out;                    // [B,S,D] fp32
    float* wout = out + (size_t)Bb*Ss*Dd;           // [B,H,S,S] fp32

    // d_ws layout: 33.5 MB (identical footprint to the passing round-1 run)
    u16* qs   = (u16*)d_ws;                         // [B,H,S,DH] 8 MB
    u16* ksb  = qs  + (size_t)Bb*Hh*Ss*DHh;         // 8 MB
    u16* vt   = ksb + (size_t)Bb*Hh*Ss*DHh;         // [B,H,DH,S] 8 MB
    u16* attn = vt  + (size_t)Bb*Hh*Ss*DHh;         // [B,S,D] 8 MB
    float* mstat = (float*)(attn + (size_t)Bb*Ss*Dd);
    float* lstat = mstat + (size_t)Bb*Hh*Ss;
    u32* mbits = (u32*)(lstat + (size_t)Bb*Hh*Ss);  // 1 MB

    // Split scratch lives in the d_out weights region (537 MB): dead until
    // attn_wpv overwrites every element of wout AFTER the projections.
    u16* Ahi = (u16*)wout;                          // [B*S, D] 8 MB
    u16* Alo = Ahi + (size_t)Bb*Ss*Dd;              // 8 MB
    u16* Whi = Alo + (size_t)Bb*Ss*Dd;              // [D, D] 2 MB
    u16* Wlo = Whi + (size_t)Dd*Dd;                 // 2 MB
    // Dense-W split (needed AFTER attn_wpv) reuses the then-dead qs buffer.
    u16* Whi2 = qs;
    u16* Wlo2 = qs + (size_t)Dd*Dd;

    const int M = Bb*Ss, N = Dd, K = Dd;
    const int n8_in = M*K/8, n8_w = N*K/8;
    dim3 gg(M/128, N/128), bb(256);

    mask_pack<<<dim3((Bb*Ss*Ss/32)/256), bb, 0, stream>>>(mask, mbits);

    // Q projection
    split_hilo<<<dim3((n8_in+255)/256), bb, 0, stream>>>(q, Ahi, Alo, n8_in);
    split_hilo<<<dim3((n8_w+255)/256),  bb, 0, stream>>>(wq_w, Whi, Wlo, n8_w);
    gemm_fused<1,3><<<gg, bb, 0, stream>>>(Ahi, Alo, Whi, Wlo, wq_b, qs, M, N, K);
    // K projection
    split_hilo<<<dim3((n8_in+255)/256), bb, 0, stream>>>(k, Ahi, Alo, n8_in);
    split_hilo<<<dim3((n8_w+255)/256),  bb, 0, stream>>>(wk_w, Whi, Wlo, n8_w);
    gemm_fused<1,3><<<gg, bb, 0, stream>>>(Ahi, Alo, Whi, Wlo, wk_b, ksb, M, N, K);
    // V projection (transposed store)
    split_hilo<<<dim3((n8_in+255)/256), bb, 0, stream>>>(v, Ahi, Alo, n8_in);
    split_hilo<<<dim3((n8_w+255)/256),  bb, 0, stream>>>(wv_w, Whi, Wlo, n8_w);
    gemm_fused<2,3><<<gg, bb, 0, stream>>>(Ahi, Alo, Whi, Wlo, wv_b, vt, M, N, K);

    dim3 ga(Ss/128, Bb*Hh);
    attn_stats_mfma<<<ga, bb, 0, stream>>>(qs, ksb, mbits, mstat, lstat);
    attn_wpv      <<<ga, bb, 0, stream>>>(qs, ksb, vt, mbits, mstat, lstat, wout, attn);

    // Dense projection: A = attn (bf16-exact), W split 2-term; qs is dead now.
    split_hilo<<<dim3((n8_w+255)/256), bb, 0, stream>>>(dense_w, Whi2, Wlo2, n8_w);
    gemm_fused<0,2><<<gg, bb, 0, stream>>>(attn, attn, Whi2, Wlo2, dense_b, out, M, N, K);
}

// Round 5
// 1080.586 us; speedup vs baseline: 1.8491x; 1.0308x over previous
//
#include <hip/hip_runtime.h>
#include <math.h>

// Problem constants (B=2, S=2048, D=1024, H=16, DH=64)
#define Bb 2
#define Ss 2048
#define Dd 1024
#define Hh 16
#define DHh 64

typedef unsigned short u16;
typedef unsigned int u32;
typedef __attribute__((ext_vector_type(8))) short short8;   // 8 bf16 = 4 VGPR
typedef __attribute__((ext_vector_type(4))) float f32x4;

#define LOG2E 1.44269504088896340736f

__device__ __forceinline__ u16 fb(float f){
    u32 x = __float_as_uint(f);
    return (u16)((x + 0x7fffu + ((x>>16)&1u)) >> 16);   // RNE bf16
}
__device__ __forceinline__ float bf2f(u16 h){
    return __uint_as_float((u32)h << 16);
}

// ---------------------------------------------------------------------------
// Batched fp32 -> (hi, lo) bf16 split. One dispatch for 6 arrays.
// ---------------------------------------------------------------------------
struct SplitJob { const float* src; u16* hi; u16* lo; int n8; };
struct SplitJobs { SplitJob j[6]; };

__global__ __launch_bounds__(256) void split_batch(SplitJobs jobs)
{
    const SplitJob J = jobs.j[blockIdx.y];
    const int i = blockIdx.x*256 + threadIdx.x;
    if (i >= J.n8) return;
    float4 a = ((const float4*)J.src)[i*2];
    float4 b = ((const float4*)J.src)[i*2+1];
    float f[8] = {a.x,a.y,a.z,a.w,b.x,b.y,b.z,b.w};
    u16 h8[8], l8[8];
    #pragma unroll
    for (int j=0;j<8;j++){
        u16 h = fb(f[j]);
        h8[j] = h;
        l8[j] = fb(f[j] - bf2f(h));
    }
    *(uint4*)(J.hi + (size_t)i*8) = *(const uint4*)h8;
    *(uint4*)(J.lo + (size_t)i*8) = *(const uint4*)l8;
}

__global__ __launch_bounds__(256) void split_hilo(
    const float* __restrict__ x, u16* __restrict__ hi, u16* __restrict__ lo,
    int n8)
{
    const int i = blockIdx.x*256 + threadIdx.x;
    if (i >= n8) return;
    float4 a = ((const float4*)x)[i*2];
    float4 b = ((const float4*)x)[i*2+1];
    float f[8] = {a.x,a.y,a.z,a.w,b.x,b.y,b.z,b.w};
    u16 h8[8], l8[8];
    #pragma unroll
    for (int j=0;j<8;j++){
        u16 h = fb(f[j]);
        h8[j] = h;
        l8[j] = fb(f[j] - bf2f(h));
    }
    *(uint4*)(hi + (size_t)i*8) = *(const uint4*)h8;
    *(uint4*)(lo + (size_t)i*8) = *(const uint4*)l8;
}

// ---------------------------------------------------------------------------
// Fused Q/K/V projection GEMM, hi/lo 3-term, single K-loop.
// Grid (32, 24): blockIdx.y -> proj = y>>3 (0=Q,1=K,2=V), n-tile = y&7.
// 768 blocks = 3 blocks/CU (vs 256 = 1/CU before) -> 3 waves/SIMD latency
// hiding. Same per-output accumulation order as r4 (absmax-invariant).
// proj 0/1: bf16 split-head store [B,H,S,DH]; proj 2: transposed store
// [B,H,DH,S] via P/Q operand-role swap (s-dim on lane&15 -> coalesced).
// mfma(P,Q): C row-dim (P row) = lg*4+r, col-dim (Q row) = lr  [verified r1].
// ---------------------------------------------------------------------------
__global__ __launch_bounds__(256, 3) void gemm_qkv(
    const u16* __restrict__ qh, const u16* __restrict__ ql,
    const u16* __restrict__ kh, const u16* __restrict__ kl,
    const u16* __restrict__ vh, const u16* __restrict__ vl,
    const u16* __restrict__ wqh, const u16* __restrict__ wql,
    const u16* __restrict__ wkh, const u16* __restrict__ wkl,
    const u16* __restrict__ wvh, const u16* __restrict__ wvl,
    const float* __restrict__ bq, const float* __restrict__ bk,
    const float* __restrict__ bv,
    u16* __restrict__ qs, u16* __restrict__ ksb, u16* __restrict__ vt)
{
    const int K = Dd;
    const int t = threadIdx.x, lane = t & 63, wave = t >> 6;
    const int lr = lane & 15, lg = lane >> 4;
    const int bm = blockIdx.x;
    const int proj = blockIdx.y >> 3, bnn = blockIdx.y & 7;
    const int wr = wave >> 1, wc = wave & 1;
    const int am0 = bm*128 + wr*64;
    const int wn0 = bnn*128 + wc*64;

    const u16* Ah = proj==0 ? qh : proj==1 ? kh : vh;
    const u16* Al = proj==0 ? ql : proj==1 ? kl : vl;
    const u16* Wh = proj==0 ? wqh : proj==1 ? wkh : wvh;
    const u16* Wl = proj==0 ? wql : proj==1 ? wkl : wvl;
    const float* bias = proj==0 ? bq : proj==1 ? bk : bv;

    const bool swap = (proj==2);
    const u16* P0 = swap ? Wh : Ah;
    const u16* P1 = swap ? Wl : Al;
    const u16* Q0 = swap ? Ah : Wh;
    const u16* Q1 = swap ? Al : Wl;
    const int prow = swap ? wn0 : am0;
    const int qrow = swap ? am0 : wn0;
    const u16* Pb0 = P0 + (size_t)(prow + lr)*K + lg*8;
    const u16* Pb1 = P1 + (size_t)(prow + lr)*K + lg*8;
    const u16* Qb0 = Q0 + (size_t)(qrow + lr)*K + lg*8;
    const u16* Qb1 = Q1 + (size_t)(qrow + lr)*K + lg*8;

    f32x4 acc[4][4];
    #pragma unroll
    for (int i=0;i<4;i++)
        #pragma unroll
        for (int j=0;j<4;j++){ f32x4 z={0.f,0.f,0.f,0.f}; acc[i][j]=z; }

    for (int kt=0; kt<K; kt+=32){
        short8 pf0[4], pf1[4], qf0[4], qf1[4];
        #pragma unroll
        for (int i=0;i<4;i++){
            pf0[i] = *(const short8*)(Pb0 + (size_t)(i*16)*K + kt);
            qf0[i] = *(const short8*)(Qb0 + (size_t)(i*16)*K + kt);
            qf1[i] = *(const short8*)(Qb1 + (size_t)(i*16)*K + kt);
            pf1[i] = *(const short8*)(Pb1 + (size_t)(i*16)*K + kt);
        }
        #pragma unroll
        for (int i=0;i<4;i++)
            #pragma unroll
            for (int j=0;j<4;j++){
                acc[i][j] = __builtin_amdgcn_mfma_f32_16x16x32_bf16(
                    pf0[i], qf0[j], acc[i][j], 0,0,0);
                acc[i][j] = __builtin_amdgcn_mfma_f32_16x16x32_bf16(
                    pf0[i], qf1[j], acc[i][j], 0,0,0);
                acc[i][j] = __builtin_amdgcn_mfma_f32_16x16x32_bf16(
                    pf1[i], qf0[j], acc[i][j], 0,0,0);
            }
    }

    if (!swap){
        u16* op = proj==0 ? qs : ksb;
        float bq4[4];
        #pragma unroll
        for (int j=0;j<4;j++) bq4[j] = bias[wn0 + j*16 + lr];
        #pragma unroll
        for (int i=0;i<4;i++)
            #pragma unroll
            for (int r=0;r<4;r++){
                const int m = am0 + i*16 + lg*4 + r;
                const int b = m >> 11, s = m & (Ss-1);
                #pragma unroll
                for (int j=0;j<4;j++){
                    const int n = wn0 + j*16 + lr;
                    const int h = n >> 6, d = n & (DHh-1);
                    op[((size_t)((b*Hh + h)*Ss + s))*DHh + d] =
                        fb(acc[i][j][r] + bq4[j]);
                }
            }
    } else {
        // P=W (n-dim on i, lg*4+r), Q=A (m-dim on j, lr)
        float bp[4][4];
        #pragma unroll
        for (int i=0;i<4;i++){
            float4 bvv = *(const float4*)(bias + wn0 + i*16 + lg*4);
            bp[i][0]=bvv.x; bp[i][1]=bvv.y; bp[i][2]=bvv.z; bp[i][3]=bvv.w;
        }
        #pragma unroll
        for (int i=0;i<4;i++)
            #pragma unroll
            for (int r=0;r<4;r++){
                const int n = wn0 + i*16 + lg*4 + r;
                const int h = n >> 6, d = n & (DHh-1);
                #pragma unroll
                for (int j=0;j<4;j++){
                    const int m = am0 + j*16 + lr;
                    const int b = m >> 11, s = m & (Ss-1);
                    vt[((size_t)((b*Hh + h)*DHh + d))*Ss + s] =
                        fb(acc[i][j][r] + bp[i][r]);
                }
            }
    }
}

// ---------------------------------------------------------------------------
// Dense GEMM: out = A@W0^T + A@W1^T + bias, fp32 store.
// Block tile 128x64 -> grid (32,16) = 512 blocks = 2 blocks/CU (was 1).
// 4 waves = 2(m) x 2(n); wave tile 64x32. Same per-output term order as r4.
// ---------------------------------------------------------------------------
__global__ __launch_bounds__(256) void gemm_dense(
    const u16* __restrict__ A, const u16* __restrict__ W0,
    const u16* __restrict__ W1, const float* __restrict__ bias,
    float* __restrict__ out)
{
    const int K = Dd, N = Dd;
    const int t = threadIdx.x, lane = t & 63, wave = t >> 6;
    const int lr = lane & 15, lg = lane >> 4;
    const int bm = blockIdx.x, bn = blockIdx.y;
    const int wr = wave >> 1, wc = wave & 1;
    const int am0 = bm*128 + wr*64;
    const int wn0 = bn*64 + wc*32;

    const u16* Pb0 = A  + (size_t)(am0 + lr)*K + lg*8;
    const u16* Qb0 = W0 + (size_t)(wn0 + lr)*K + lg*8;
    const u16* Qb1 = W1 + (size_t)(wn0 + lr)*K + lg*8;

    f32x4 acc[4][2];
    #pragma unroll
    for (int i=0;i<4;i++)
        #pragma unroll
        for (int j=0;j<2;j++){ f32x4 z={0.f,0.f,0.f,0.f}; acc[i][j]=z; }

    for (int kt=0; kt<K; kt+=32){
        short8 pf0[4], qf0[2], qf1[2];
        #pragma unroll
        for (int i=0;i<4;i++)
            pf0[i] = *(const short8*)(Pb0 + (size_t)(i*16)*K + kt);
        #pragma unroll
        for (int j=0;j<2;j++){
            qf0[j] = *(const short8*)(Qb0 + (size_t)(j*16)*K + kt);
            qf1[j] = *(const short8*)(Qb1 + (size_t)(j*16)*K + kt);
        }
        #pragma unroll
        for (int i=0;i<4;i++)
            #pragma unroll
            for (int j=0;j<2;j++){
                acc[i][j] = __builtin_amdgcn_mfma_f32_16x16x32_bf16(
                    pf0[i], qf0[j], acc[i][j], 0,0,0);
                acc[i][j] = __builtin_amdgcn_mfma_f32_16x16x32_bf16(
                    pf0[i], qf1[j], acc[i][j], 0,0,0);
            }
    }

    float bq[2];
    #pragma unroll
    for (int j=0;j<2;j++) bq[j] = bias[wn0 + j*16 + lr];
    #pragma unroll
    for (int i=0;i<4;i++)
        #pragma unroll
        for (int r=0;r<4;r++){
            const int m = am0 + i*16 + lg*4 + r;
            #pragma unroll
            for (int j=0;j<2;j++)
                out[(size_t)m*N + wn0 + j*16 + lr] = acc[i][j][r] + bq[j];
        }
}

// ---------------------------------------------------------------------------
// mask [B,1,S,S] int32 -> bitmask [B,S,S/32]
// ---------------------------------------------------------------------------
__global__ __launch_bounds__(256) void mask_pack(
    const int* __restrict__ mask, u32* __restrict__ mbits)
{
    const size_t w = (size_t)blockIdx.x*256 + threadIdx.x;
    const int* p = mask + w*32;
    u32 bits = 0;
    #pragma unroll
    for (int i=0;i<32;i+=4){
        int4 v = *(const int4*)(p + i);
        bits |= (u32)(v.x!=0) << i;
        bits |= (u32)(v.y!=0) << (i+1);
        bits |= (u32)(v.z!=0) << (i+2);
        bits |= (u32)(v.w!=0) << (i+3);
    }
    mbits[w] = bits;
}

// ---------------------------------------------------------------------------
// S1: per-row softmax stats (m, l) via MFMA QK^T. No LDS. log2-domain stats.
// ---------------------------------------------------------------------------
__global__ __launch_bounds__(256) void attn_stats_mfma(
    const u16* __restrict__ Q, const u16* __restrict__ K,
    const u32* __restrict__ mbits,
    float* __restrict__ mstat, float* __restrict__ lstat)
{
    const int t = threadIdx.x;
    const int lane = t & 63, wave = t >> 6;
    const int qt = blockIdx.x, bh = blockIdx.y;
    const int b = bh >> 4;
    const int qr0 = qt*128 + wave*32;
    const u16* qb = Q + ((size_t)bh*Ss + qr0)*DHh;
    const u16* kb = K + (size_t)bh*Ss*DHh;
    const u32* mb = mbits + (size_t)b*Ss*(Ss/32);

    const int lr = lane & 15;
    const int lg = lane >> 4;

    short8 aq[2][2];
    #pragma unroll
    for (int s2=0;s2<2;s2++)
        #pragma unroll
        for (int dh=0; dh<2; dh++)
            aq[s2][dh] = *(const short8*)(qb + (size_t)(s2*16 + lr)*DHh + dh*32 + lg*8);

    int qv[8];
    #pragma unroll
    for (int idx=0; idx<8; idx++)
        qv[idx] = qr0 + (idx>>2)*16 + lg*4 + (idx&3);

    float m[8], l[8];
    #pragma unroll
    for (int i=0;i<8;i++){ m[i]=-1e30f; l[i]=0.f; }

    const float SC = 0.125f * LOG2E;

    for (int k0=0; k0<Ss; k0+=32){
        u32 mw[8];
        #pragma unroll
        for (int idx=0; idx<8; idx++)
            mw[idx] = mb[(size_t)qv[idx]*(Ss/32) + (k0>>5)];
        #pragma unroll
        for (int h2=0; h2<2; h2++){
            const u16* kr = kb + (size_t)(k0 + h2*16 + lr)*DHh + lg*8;
            short8 b0 = *(const short8*)kr;
            short8 b1 = *(const short8*)(kr + 32);
            f32x4 z = {0.f,0.f,0.f,0.f};
            f32x4 s0 = __builtin_amdgcn_mfma_f32_16x16x32_bf16(aq[0][0], b0, z, 0,0,0);
            s0 = __builtin_amdgcn_mfma_f32_16x16x32_bf16(aq[0][1], b1, s0, 0,0,0);
            f32x4 s1 = __builtin_amdgcn_mfma_f32_16x16x32_bf16(aq[1][0], b0, z, 0,0,0);
            s1 = __builtin_amdgcn_mfma_f32_16x16x32_bf16(aq[1][1], b1, s1, 0,0,0);
            #pragma unroll
            for (int idx=0; idx<8; idx++){
                const int s2 = idx>>2, r = idx&3;
                float sc = (s2 ? s1[r] : s0[r]) * SC;
                float x  = ((mw[idx] >> (h2*16 + lr)) & 1) ? sc : -INFINITY;
                float mo = m[idx];
                float mn = fmaxf(mo, x);
                float e  = exp2f(fminf(mo, x) - mn);   // 1 exp2 per element
                bool gt  = x > mo;
                l[idx] = fmaf(l[idx], gt ? e : 1.f, gt ? 1.f : e);
                m[idx] = mn;
            }
        }
    }

    #pragma unroll
    for (int idx=0; idx<8; idx++){
        float mm = m[idx], ll = l[idx];
        #pragma unroll
        for (int off=1; off<16; off<<=1){
            float mo = __shfl_xor(mm, off, 64);
            float lo = __shfl_xor(ll, off, 64);
            float mn = fmaxf(mm, mo);
            ll = ll*exp2f(mm-mn) + lo*exp2f(mo-mn);
            mm = mn;
        }
        if (lr == 0){
            mstat[(size_t)bh*Ss + qv[idx]] = mm;   // log2 domain
            lstat[(size_t)bh*Ss + qv[idx]] = ll;
        }
    }
}

// ---------------------------------------------------------------------------
// S2 fused: recompute scores, normalize (log2 domain), stream fp32 weights,
// PV via MFMA against transposed V.
// ---------------------------------------------------------------------------
__global__ __launch_bounds__(256) void attn_wpv(
    const u16* __restrict__ Q, const u16* __restrict__ K,
    const u16* __restrict__ Vt, const u32* __restrict__ mbits,
    const float* __restrict__ mstat, const float* __restrict__ lstat,
    float* __restrict__ wout, u16* __restrict__ attn)
{
    __shared__ __align__(16) u16 plds[4][32][40];
    const int t = threadIdx.x;
    const int lane = t & 63, wave = t >> 6;
    const int qt = blockIdx.x, bh = blockIdx.y;
    const int b = bh >> 4, h = bh & 15;
    const int qr0 = qt*128 + wave*32;
    const u16* qb  = Q  + ((size_t)bh*Ss + qr0)*DHh;
    const u16* kb  = K  + (size_t)bh*Ss*DHh;
    const u16* vtb = Vt + (size_t)bh*DHh*Ss;
    const u32* mb  = mbits + (size_t)b*Ss*(Ss/32);
    float* wop = wout + (size_t)bh*Ss*Ss;

    const int lr = lane & 15;
    const int lg = lane >> 4;

    short8 aq[2][2];
    #pragma unroll
    for (int s2=0;s2<2;s2++)
        #pragma unroll
        for (int dh=0; dh<2; dh++)
            aq[s2][dh] = *(const short8*)(qb + (size_t)(s2*16 + lr)*DHh + dh*32 + lg*8);

    int qv[8];
    float mrow[8], li[8];
    #pragma unroll
    for (int idx=0; idx<8; idx++){
        qv[idx] = qr0 + (idx>>2)*16 + lg*4 + (idx&3);
        mrow[idx] = mstat[(size_t)bh*Ss + qv[idx]];   // log2 domain
        float lv  = lstat[(size_t)bh*Ss + qv[idx]];
        li[idx] = lv > 0.f ? 1.f/lv : 0.f;
    }

    f32x4 acc_o[2][4];
    #pragma unroll
    for (int s2=0;s2<2;s2++)
        #pragma unroll
        for (int dt=0;dt<4;dt++){
            f32x4 z = {0.f,0.f,0.f,0.f};
            acc_o[s2][dt] = z;
        }

    const float SC = 0.125f * LOG2E;

    for (int k0=0; k0<Ss; k0+=32){
        u32 mw[8];
        #pragma unroll
        for (int idx=0; idx<8; idx++)
            mw[idx] = mb[(size_t)qv[idx]*(Ss/32) + (k0>>5)];
        #pragma unroll
        for (int h2=0; h2<2; h2++){
            const int kk = k0 + h2*16;
            const u16* kr = kb + (size_t)(kk + lr)*DHh + lg*8;
            short8 b0 = *(const short8*)kr;
            short8 b1 = *(const short8*)(kr + 32);
            f32x4 z = {0.f,0.f,0.f,0.f};
            f32x4 s0 = __builtin_amdgcn_mfma_f32_16x16x32_bf16(aq[0][0], b0, z, 0,0,0);
            s0 = __builtin_amdgcn_mfma_f32_16x16x32_bf16(aq[0][1], b1, s0, 0,0,0);
            f32x4 s1 = __builtin_amdgcn_mfma_f32_16x16x32_bf16(aq[1][0], b0, z, 0,0,0);
            s1 = __builtin_amdgcn_mfma_f32_16x16x32_bf16(aq[1][1], b1, s1, 0,0,0);
            #pragma unroll
            for (int idx=0; idx<8; idx++){
                const int s2 = idx>>2, r = idx&3;
                float sc  = (s2 ? s1[r] : s0[r]) * SC;
                float wgt = ((mw[idx] >> (h2*16 + lr)) & 1)
                          ? exp2f(sc - mrow[idx]) * li[idx] : 0.f;
                __builtin_nontemporal_store(wgt, wop + (size_t)qv[idx]*Ss + kk + lr);
                plds[wave][s2*16 + lg*4 + r][h2*16 + lr] = fb(wgt);
            }
        }
        short8 pa0 = *(const short8*)&plds[wave][lr][lg*8];
        short8 pa1 = *(const short8*)&plds[wave][16 + lr][lg*8];
        #pragma unroll
        for (int dt=0; dt<4; dt++){
            short8 vb = *(const short8*)(vtb + (size_t)(dt*16 + lr)*Ss + k0 + lg*8);
            acc_o[0][dt] = __builtin_amdgcn_mfma_f32_16x16x32_bf16(pa0, vb, acc_o[0][dt], 0,0,0);
            acc_o[1][dt] = __builtin_amdgcn_mfma_f32_16x16x32_bf16(pa1, vb, acc_o[1][dt], 0,0,0);
        }
    }

    u16* ab = attn + (size_t)b*Ss*Dd + (size_t)h*DHh;
    #pragma unroll
    for (int s2=0;s2<2;s2++)
        #pragma unroll
        for (int dt=0;dt<4;dt++)
            #pragma unroll
            for (int r=0;r<4;r++){
                const int q = qr0 + s2*16 + lg*4 + r;
                ab[(size_t)q*Dd + dt*16 + lr] = fb(acc_o[s2][dt][r]);
            }
}

// ---------------------------------------------------------------------------
extern "C" void kernel_launch(void* const* d_in, const int* in_sizes, int n_in,
                              void* d_out, int out_size, void* d_ws, size_t ws_size,
                              hipStream_t stream) {
    const float* q      = (const float*)d_in[0];
    const float* k      = (const float*)d_in[1];
    const float* v      = (const float*)d_in[2];
    const int*   mask   = (const int*)d_in[3];
    const float* wq_w   = (const float*)d_in[4];
    const float* wq_b   = (const float*)d_in[5];
    const float* wk_w   = (const float*)d_in[6];
    const float* wk_b   = (const float*)d_in[7];
    const float* wv_w   = (const float*)d_in[8];
    const float* wv_b   = (const float*)d_in[9];
    const float* dense_w= (const float*)d_in[10];
    const float* dense_b= (const float*)d_in[11];

    float* out  = (float*)d_out;                    // [B,S,D] fp32
    float* wout = out + (size_t)Bb*Ss*Dd;           // [B,H,S,S] fp32

    // d_ws layout: ~35 MB (same as passing rounds)
    u16* qs   = (u16*)d_ws;                         // [B,H,S,DH] 8 MB
    u16* ksb  = qs  + (size_t)Bb*Hh*Ss*DHh;         // 8 MB
    u16* vt   = ksb + (size_t)Bb*Hh*Ss*DHh;         // [B,H,DH,S] 8 MB
    u16* attn = vt  + (size_t)Bb*Hh*Ss*DHh;         // [B,S,D] 8 MB
    float* mstat = (float*)(attn + (size_t)Bb*Ss*Dd);
    float* lstat = mstat + (size_t)Bb*Hh*Ss;
    u32* mbits = (u32*)(lstat + (size_t)Bb*Hh*Ss);  // 1 MB

    // Split scratch in the d_out weights region (537 MB): dead until
    // attn_wpv overwrites all of wout AFTER the projections. ~63 MB used.
    const size_t NA = (size_t)Bb*Ss*Dd;             // 4.19M elems
    const size_t NW = (size_t)Dd*Dd;                // 1.05M elems
    u16* SB  = (u16*)wout;
    u16* qhi = SB;            u16* qlo = qhi + NA;
    u16* khi = qlo + NA;      u16* klo = khi + NA;
    u16* vhi = klo + NA;      u16* vlo = vhi + NA;
    u16* wqh = vlo + NA;      u16* wql = wqh + NW;
    u16* wkh = wql + NW;      u16* wkl = wkh + NW;
    u16* wvh = wkl + NW;      u16* wvl = wvh + NW;
    // Dense-W split (needed AFTER attn_wpv) reuses the then-dead qs buffer.
    u16* Whi2 = qs;
    u16* Wlo2 = qs + NW;

    const int M = Bb*Ss;
    const int n8A = (int)(NA/8), n8W = (int)(NW/8);
    dim3 bb(256);

    mask_pack<<<dim3((Bb*Ss*Ss/32)/256), bb, 0, stream>>>(mask, mbits);

    SplitJobs jobs;
    jobs.j[0] = { q,    qhi, qlo, n8A };
    jobs.j[1] = { k,    khi, klo, n8A };
    jobs.j[2] = { v,    vhi, vlo, n8A };
    jobs.j[3] = { wq_w, wqh, wql, n8W };
    jobs.j[4] = { wk_w, wkh, wkl, n8W };
    jobs.j[5] = { wv_w, wvh, wvl, n8W };
    split_batch<<<dim3(n8A/256, 6), bb, 0, stream>>>(jobs);

    // Fused Q/K/V projections: grid 768 blocks = 3 blocks/CU
    gemm_qkv<<<dim3(M/128, 24), bb, 0, stream>>>(
        qhi,qlo, khi,klo, vhi,vlo, wqh,wql, wkh,wkl, wvh,wvl,
        wq_b, wk_b, wv_b, qs, ksb, vt);

    dim3 ga(Ss/128, Bb*Hh);
    attn_stats_mfma<<<ga, bb, 0, stream>>>(qs, ksb, mbits, mstat, lstat);
    attn_wpv      <<<ga, bb, 0, stream>>>(qs, ksb, vt, mbits, mstat, lstat, wout, attn);

    // Dense projection: A = attn (bf16-exact), W split 2-term; qs dead now.
    split_hilo<<<dim3((n8W+255)/256), bb, 0, stream>>>(dense_w, Whi2, Wlo2, n8W);
    gemm_dense<<<dim3(M/128, Dd/64), bb, 0, stream>>>(attn, Whi2, Wlo2, dense_b, out);
}